// Round 2
// baseline (900.382 us; speedup 1.0000x reference)
//
#include <hip/hip_runtime.h>
#include <math.h>

typedef short bf16x8 __attribute__((ext_vector_type(8)));
typedef float f32x4 __attribute__((ext_vector_type(4)));

#define HH 8
#define NN 4096
#define DQK 320   // hi feature dim: [0..239] ip, [240..255] s, [256..303] dist_hi, [304..319] 0
#define DML 128   // mid/lo matrix: [0..47] dist_mid, [48..63] 0, [64..111] dist_lo, [112..127] 0
#define DV 272
#define BM 128
#define BN 64
#define NWAVE 4
#define MW 32
#define KT_LD 328 // 656B row stride -> 2-way bank aliasing (free)
#define KM_LD 72
#define VT_LD 72
#define P_LD 72

__device__ __forceinline__ unsigned short f2bf(float f) {
    unsigned int u = __float_as_uint(f);
    u = (u + 0x7fffu + ((u >> 16) & 1u)) >> 16;   // RNE
    return (unsigned short)u;
}
__device__ __forceinline__ float bf2f(unsigned short h) {
    return __uint_as_float(((unsigned int)h) << 16);
}

// ---- stage 1a: build split-precision bf16 feature matrices ----
__global__ void feat_kernel(const float* __restrict__ mv,
                            const float* __restrict__ sv,
                            const float* __restrict__ basis,
                            float scale,
                            unsigned short* __restrict__ dhi,
                            unsigned short* __restrict__ dml)
{
    __shared__ float sb[150];
    int t = threadIdx.x;
    if (t < 150) sb[t] = basis[t];
    __syncthreads();
    int row = blockIdx.x * 32 + (t >> 3);   // (h*4096+n)
    int c = t & 7;
    const float* m = mv + (size_t)row * 256 + c * 32;
    float f[32];
    #pragma unroll
    for (int i = 0; i < 8; ++i) {
        float4 v = ((const float4*)m)[i];
        f[i*4+0] = v.x; f[i*4+1] = v.y; f[i*4+2] = v.z; f[i*4+3] = v.w;
    }
    unsigned short* d  = dhi + (size_t)row * DQK;
    unsigned short* ml = dml + (size_t)row * DML;
    #pragma unroll
    for (int j = 0; j < 30; ++j)
        d[c*30 + j] = f2bf(f[1+j] * scale);
    float nn = 1.0f / sqrtf(f[5]*f[5] + 0.001f);
    float tn[5];
    #pragma unroll
    for (int x = 0; x < 5; ++x) tn[x] = f[1+x] * nn;
    #pragma unroll
    for (int z = 0; z < 6; ++z) {
        float acc = 0.f;
        #pragma unroll
        for (int x = 0; x < 5; ++x) {
            #pragma unroll
            for (int y = 0; y < 5; ++y)
                acc = fmaf(sb[(x*5+y)*6 + z] * tn[x], tn[y], acc);
        }
        acc *= scale;
        unsigned short hi = f2bf(acc);
        float r1 = acc - bf2f(hi);
        unsigned short mi = f2bf(r1);
        float r2 = r1 - bf2f(mi);
        unsigned short lo = f2bf(r2);
        d[256 + c*6 + z] = hi;
        ml[c*6 + z]      = mi;
        ml[64 + c*6 + z] = lo;
    }
    if (c < 2) {
        #pragma unroll
        for (int i = 0; i < 8; ++i) {
            int si = c*8 + i;
            d[240 + si] = f2bf(sv[(size_t)row*16 + si] * scale);
        }
    } else if (c == 2) {
        #pragma unroll
        for (int i = 0; i < 8; ++i) d[304 + i] = 0;
    } else if (c == 3) {
        #pragma unroll
        for (int i = 0; i < 8; ++i) d[312 + i] = 0;
    } else if (c == 4) {
        #pragma unroll
        for (int i = 0; i < 8; ++i) ml[48 + i] = 0;
    } else if (c == 5) {
        #pragma unroll
        for (int i = 0; i < 8; ++i) ml[56 + i] = 0;
    } else if (c == 6) {
        #pragma unroll
        for (int i = 0; i < 8; ++i) ml[112 + i] = 0;
    } else {
        #pragma unroll
        for (int i = 0; i < 8; ++i) ml[120 + i] = 0;
    }
}

// ---- stage 1b: V -> transposed bf16 [8][272][4096] ----
__global__ void vtrans_kernel(const float* __restrict__ vmv,
                              const float* __restrict__ vs,
                              unsigned short* __restrict__ dst)
{
    __shared__ unsigned short tile[64][DV];
    int blk = blockIdx.x;
    int h = blk >> 6;
    int n0 = (blk & 63) << 6;
    int t = threadIdx.x;
    #pragma unroll
    for (int it = 0; it < 16; ++it) {
        int v = t + it*256;
        int r = v >> 6;
        int sg = v & 63;
        float4 x = *(const float4*)(vmv + ((size_t)(h*NN + n0 + r))*256 + sg*4);
        tile[r][sg*4+0] = f2bf(x.x);
        tile[r][sg*4+1] = f2bf(x.y);
        tile[r][sg*4+2] = f2bf(x.z);
        tile[r][sg*4+3] = f2bf(x.w);
    }
    #pragma unroll
    for (int it = 0; it < 4; ++it) {
        int v = t + it*256;
        int r = v >> 4;
        int si = v & 15;
        tile[r][256 + si] = f2bf(vs[((size_t)(h*NN + n0 + r))*16 + si]);
    }
    __syncthreads();
    #pragma unroll
    for (int it = 0; it < 17; ++it) {      // 272 rows * 16 segs = 4352 = 17*256
        int v = t + it*256;
        int dd = v >> 4;
        int sg = v & 15;
        ushort4 o;
        o.x = tile[sg*4+0][dd];
        o.y = tile[sg*4+1][dd];
        o.z = tile[sg*4+2][dd];
        o.w = tile[sg*4+3][dd];
        *(ushort4*)(dst + ((size_t)(h*DV + dd))*NN + n0 + sg*4) = o;
    }
}

// ---- stage 2: flash attention with split-precision dist scores ----
__global__ __launch_bounds__(256, 1)
void attn_kernel(const unsigned short* __restrict__ Qf,
                 const unsigned short* __restrict__ Kf,
                 const unsigned short* __restrict__ Qml,
                 const unsigned short* __restrict__ Kml,
                 const unsigned short* __restrict__ Vt,
                 float* __restrict__ out)
{
    __shared__ __align__(16) unsigned short kt_s[BN][KT_LD];
    __shared__ __align__(16) unsigned short km_s[BN][KM_LD];
    __shared__ __align__(16) unsigned short kl_s[BN][KM_LD];
    __shared__ __align__(16) unsigned short vt_s[DV][VT_LD];
    __shared__ __align__(16) unsigned short pb_s[NWAVE][MW][P_LD];

    int blk = blockIdx.x;
    // XCD swizzle: grid=256 (8|256) -> bijective; XCD x gets head x.
    int sbk = ((blk & 7) << 5) | (blk >> 3);
    int h = sbk >> 5;
    int q0 = (sbk & 31) * BM;
    int tid = threadIdx.x;
    int w = tid >> 6;
    int lane = tid & 63;
    int l15 = lane & 15;
    int l4 = lane >> 4;

    // Q fragments in registers
    const unsigned short* qb = Qf + ((size_t)h*NN + q0 + w*MW + l15) * DQK + l4*8;
    const unsigned short* qm = Qml + ((size_t)h*NN + q0 + w*MW + l15) * DML + l4*8;
    bf16x8 qhi[2][10], qmid[2][2], qlo[2][2];
    #pragma unroll
    for (int rt = 0; rt < 2; ++rt) {
        #pragma unroll
        for (int ks = 0; ks < 10; ++ks)
            qhi[rt][ks] = *(const bf16x8*)(qb + rt*16*DQK + ks*32);
        #pragma unroll
        for (int ks = 0; ks < 2; ++ks) {
            qmid[rt][ks] = *(const bf16x8*)(qm + rt*16*DML + ks*32);
            qlo[rt][ks]  = *(const bf16x8*)(qm + rt*16*DML + 64 + ks*32);
        }
    }

    f32x4 zero = {0.f, 0.f, 0.f, 0.f};
    f32x4 oacc[2][17];
    #pragma unroll
    for (int rt = 0; rt < 2; ++rt)
        #pragma unroll
        for (int ct = 0; ct < 17; ++ct)
            oacc[rt][ct] = zero;
    float mrow[2][4], lrow[2][4];
    #pragma unroll
    for (int rt = 0; rt < 2; ++rt)
        #pragma unroll
        for (int j = 0; j < 4; ++j) { mrow[rt][j] = -__builtin_inff(); lrow[rt][j] = 0.f; }

    const unsigned short* kh  = Kf  + (size_t)h*NN*DQK;
    const unsigned short* kmh = Kml + (size_t)h*NN*DML;
    const unsigned short* vh  = Vt  + (size_t)h*DV*NN;

    for (int kt0 = 0; kt0 < NN; kt0 += BN) {
        // stage K hi tile: 64 rows * 40 16B-segs = 2560 = 10*256
        #pragma unroll
        for (int it = 0; it < 10; ++it) {
            int v = tid + it*256;
            int r = v / 40;
            int sg = v - r*40;
            bf16x8 x = *(const bf16x8*)(kh + ((size_t)(kt0 + r))*DQK + sg*8);
            *(bf16x8*)&kt_s[r][sg*8] = x;
        }
        // stage K mid/lo tile: 64 rows * 16 segs = 1024 = 4*256
        #pragma unroll
        for (int it = 0; it < 4; ++it) {
            int v = tid + it*256;
            int r = v >> 4;
            int sg = v & 15;
            bf16x8 x = *(const bf16x8*)(kmh + ((size_t)(kt0 + r))*DML + sg*8);
            if (sg < 8) *(bf16x8*)&km_s[r][sg*8] = x;
            else        *(bf16x8*)&kl_s[r][(sg-8)*8] = x;
        }
        // stage Vt tile: 272 rows * 8 segs = 2176
        #pragma unroll
        for (int it = 0; it < 9; ++it) {
            int v = tid + it*256;
            if (v < DV*8) {
                int r = v >> 3;
                int sg = v & 7;
                bf16x8 x = *(const bf16x8*)(vh + (size_t)r*NN + kt0 + sg*8);
                *(bf16x8*)&vt_s[r][sg*8] = x;
            }
        }
        __syncthreads();

        f32x4 sacc[2][4];
        #pragma unroll
        for (int rt = 0; rt < 2; ++rt)
            #pragma unroll
            for (int ct = 0; ct < 4; ++ct)
                sacc[rt][ct] = zero;

        // ip + s dims (0..255): single bf16 pass
        #pragma unroll
        for (int ks = 0; ks < 8; ++ks) {
            bf16x8 bfr[4];
            #pragma unroll
            for (int ct = 0; ct < 4; ++ct)
                bfr[ct] = *(const bf16x8*)&kt_s[ct*16 + l15][ks*32 + l4*8];
            #pragma unroll
            for (int ct = 0; ct < 4; ++ct) {
                sacc[0][ct] = __builtin_amdgcn_mfma_f32_16x16x32_bf16(qhi[0][ks], bfr[ct], sacc[0][ct], 0, 0, 0);
                sacc[1][ct] = __builtin_amdgcn_mfma_f32_16x16x32_bf16(qhi[1][ks], bfr[ct], sacc[1][ct], 0, 0, 0);
            }
        }
        // dist dims (hi dims 256..319, 3-term split): hh, hm, mh, hl, lh, mm
        #pragma unroll
        for (int ks2 = 0; ks2 < 2; ++ks2) {
            #pragma unroll
            for (int ct = 0; ct < 4; ++ct) {
                bf16x8 bhi = *(const bf16x8*)&kt_s[ct*16 + l15][256 + ks2*32 + l4*8];
                bf16x8 bm  = *(const bf16x8*)&km_s[ct*16 + l15][ks2*32 + l4*8];
                bf16x8 bl  = *(const bf16x8*)&kl_s[ct*16 + l15][ks2*32 + l4*8];
                #pragma unroll
                for (int rt = 0; rt < 2; ++rt) {
                    f32x4 a = sacc[rt][ct];
                    a = __builtin_amdgcn_mfma_f32_16x16x32_bf16(qhi[rt][8+ks2], bhi, a, 0, 0, 0);
                    a = __builtin_amdgcn_mfma_f32_16x16x32_bf16(qhi[rt][8+ks2], bm,  a, 0, 0, 0);
                    a = __builtin_amdgcn_mfma_f32_16x16x32_bf16(qmid[rt][ks2],  bhi, a, 0, 0, 0);
                    a = __builtin_amdgcn_mfma_f32_16x16x32_bf16(qhi[rt][8+ks2], bl,  a, 0, 0, 0);
                    a = __builtin_amdgcn_mfma_f32_16x16x32_bf16(qlo[rt][ks2],   bhi, a, 0, 0, 0);
                    a = __builtin_amdgcn_mfma_f32_16x16x32_bf16(qmid[rt][ks2],  bm,  a, 0, 0, 0);
                    sacc[rt][ct] = a;
                }
            }
        }

        // online softmax; S row = rt*16 + l4*4 + j, col = ct*16 + l15
        #pragma unroll
        for (int rt = 0; rt < 2; ++rt) {
            #pragma unroll
            for (int j = 0; j < 4; ++j) {
                float tm = fmaxf(fmaxf(sacc[rt][0][j], sacc[rt][1][j]),
                                 fmaxf(sacc[rt][2][j], sacc[rt][3][j]));
                tm = fmaxf(tm, __shfl_xor(tm, 1, 64));
                tm = fmaxf(tm, __shfl_xor(tm, 2, 64));
                tm = fmaxf(tm, __shfl_xor(tm, 4, 64));
                tm = fmaxf(tm, __shfl_xor(tm, 8, 64));
                float mold = mrow[rt][j];
                float mnew = fmaxf(mold, tm);
                mrow[rt][j] = mnew;
                float p0 = __expf(sacc[rt][0][j] - mnew);
                float p1 = __expf(sacc[rt][1][j] - mnew);
                float p2 = __expf(sacc[rt][2][j] - mnew);
                float p3 = __expf(sacc[rt][3][j] - mnew);
                float rs = (p0 + p1) + (p2 + p3);
                rs += __shfl_xor(rs, 1, 64);
                rs += __shfl_xor(rs, 2, 64);
                rs += __shfl_xor(rs, 4, 64);
                rs += __shfl_xor(rs, 8, 64);
                if (__all(mnew == mold)) {
                    lrow[rt][j] += rs;
                } else {
                    float alpha = __expf(mold - mnew);   // 0 on first tile
                    lrow[rt][j] = lrow[rt][j] * alpha + rs;
                    #pragma unroll
                    for (int ct = 0; ct < 17; ++ct)
                        oacc[rt][ct][j] *= alpha;
                }
                int prow = rt*16 + l4*4 + j;
                pb_s[w][prow][ 0 + l15] = f2bf(p0);
                pb_s[w][prow][16 + l15] = f2bf(p1);
                pb_s[w][prow][32 + l15] = f2bf(p2);
                pb_s[w][prow][48 + l15] = f2bf(p3);
            }
        }

        // PV: O += P(32x64) @ V(64x272)
        #pragma unroll
        for (int ks2 = 0; ks2 < 2; ++ks2) {
            bf16x8 pa0 = *(const bf16x8*)&pb_s[w][     l15][ks2*32 + l4*8];
            bf16x8 pa1 = *(const bf16x8*)&pb_s[w][16 + l15][ks2*32 + l4*8];
            #pragma unroll
            for (int ct = 0; ct < 17; ++ct) {
                bf16x8 bv = *(const bf16x8*)&vt_s[ct*16 + l15][ks2*32 + l4*8];
                oacc[0][ct] = __builtin_amdgcn_mfma_f32_16x16x32_bf16(pa0, bv, oacc[0][ct], 0, 0, 0);
                oacc[1][ct] = __builtin_amdgcn_mfma_f32_16x16x32_bf16(pa1, bv, oacc[1][ct], 0, 0, 0);
            }
        }
        __syncthreads();
    }

    // epilogue
    const size_t mv_total = (size_t)HH * NN * 256;
    #pragma unroll
    for (int rt = 0; rt < 2; ++rt) {
        #pragma unroll
        for (int j = 0; j < 4; ++j) {
            int q = q0 + w*MW + rt*16 + l4*4 + j;
            float inv = 1.0f / lrow[rt][j];
            float* po = out + ((size_t)h*NN + q) * 256 + l15;
            #pragma unroll
            for (int ct = 0; ct < 16; ++ct)
                po[ct*16] = oacc[rt][ct][j] * inv;
            out[mv_total + ((size_t)h*NN + q)*16 + l15] = oacc[rt][16][j] * inv;
        }
    }
}

extern "C" void kernel_launch(void* const* d_in, const int* in_sizes, int n_in,
                              void* d_out, int out_size, void* d_ws, size_t ws_size,
                              hipStream_t stream)
{
    const float* q_mv = (const float*)d_in[0];
    const float* k_mv = (const float*)d_in[1];
    const float* v_mv = (const float*)d_in[2];
    const float* q_s  = (const float*)d_in[3];
    const float* k_s  = (const float*)d_in[4];
    const float* v_s  = (const float*)d_in[5];
    const float* basis_q = (const float*)d_in[6];
    const float* basis_k = (const float*)d_in[7];
    float* out = (float*)d_out;

    unsigned short* qf  = (unsigned short*)d_ws;                  // [8][4096][320]
    unsigned short* kf  = qf  + (size_t)HH*NN*DQK;                // [8][4096][320]
    unsigned short* qml = kf  + (size_t)HH*NN*DQK;                // [8][4096][128]
    unsigned short* kml = qml + (size_t)HH*NN*DML;                // [8][4096][128]
    unsigned short* vt  = kml + (size_t)HH*NN*DML;                // [8][272][4096]
    // total ws use: 76,546,048 bytes

    const float qscale = 0.05735393346764042f;  // 1/sqrt(304); k-rescale is exactly 1

    feat_kernel<<<dim3(1024), dim3(256), 0, stream>>>(q_mv, q_s, basis_q, qscale, qf, qml);
    feat_kernel<<<dim3(1024), dim3(256), 0, stream>>>(k_mv, k_s, basis_k, 1.0f, kf, kml);
    vtrans_kernel<<<dim3(512), dim3(256), 0, stream>>>(v_mv, v_s, vt);
    attn_kernel<<<dim3(256), dim3(256), 0, stream>>>(qf, kf, qml, kml, vt, out);
}

// Round 3
// 589.935 us; speedup vs baseline: 1.5262x; 1.5262x over previous
//
#include <hip/hip_runtime.h>
#include <math.h>

typedef short bf16x8 __attribute__((ext_vector_type(8)));
typedef float f32x4 __attribute__((ext_vector_type(4)));

#define HH 8
#define NN 4096
#define DQK 320   // hi feature dim: [0..239] ip, [240..255] s, [256..303] dist_hi, [304..319] 0
#define DML 128   // mid/lo matrix: [0..47] dist_mid, [48..63] 0, [64..111] dist_lo, [112..127] 0
#define DV 272
#define BM 64
#define BN 32
#define NWAVE 4
#define MW 16
#define KT_LD 328 // 656B row stride -> benign aliasing
#define KM_LD 72
#define VT_LD 40
#define P_LD 40

__device__ __forceinline__ unsigned short f2bf(float f) {
    unsigned int u = __float_as_uint(f);
    u = (u + 0x7fffu + ((u >> 16) & 1u)) >> 16;   // RNE
    return (unsigned short)u;
}
__device__ __forceinline__ float bf2f(unsigned short h) {
    return __uint_as_float(((unsigned int)h) << 16);
}

// ---- stage 1a: build split-precision bf16 feature matrices ----
__global__ void feat_kernel(const float* __restrict__ mv,
                            const float* __restrict__ sv,
                            const float* __restrict__ basis,
                            float scale,
                            unsigned short* __restrict__ dhi,
                            unsigned short* __restrict__ dml)
{
    __shared__ float sb[150];
    int t = threadIdx.x;
    if (t < 150) sb[t] = basis[t];
    __syncthreads();
    int row = blockIdx.x * 32 + (t >> 3);   // (h*4096+n)
    int c = t & 7;
    const float* m = mv + (size_t)row * 256 + c * 32;
    float f[32];
    #pragma unroll
    for (int i = 0; i < 8; ++i) {
        float4 v = ((const float4*)m)[i];
        f[i*4+0] = v.x; f[i*4+1] = v.y; f[i*4+2] = v.z; f[i*4+3] = v.w;
    }
    unsigned short* d  = dhi + (size_t)row * DQK;
    unsigned short* ml = dml + (size_t)row * DML;
    #pragma unroll
    for (int j = 0; j < 30; ++j)
        d[c*30 + j] = f2bf(f[1+j] * scale);
    float nn = 1.0f / sqrtf(f[5]*f[5] + 0.001f);
    float tn[5];
    #pragma unroll
    for (int x = 0; x < 5; ++x) tn[x] = f[1+x] * nn;
    #pragma unroll
    for (int z = 0; z < 6; ++z) {
        float acc = 0.f;
        #pragma unroll
        for (int x = 0; x < 5; ++x) {
            #pragma unroll
            for (int y = 0; y < 5; ++y)
                acc = fmaf(sb[(x*5+y)*6 + z] * tn[x], tn[y], acc);
        }
        acc *= scale;
        unsigned short hi = f2bf(acc);
        float r1 = acc - bf2f(hi);
        unsigned short mi = f2bf(r1);
        float r2 = r1 - bf2f(mi);
        unsigned short lo = f2bf(r2);
        d[256 + c*6 + z] = hi;
        ml[c*6 + z]      = mi;
        ml[64 + c*6 + z] = lo;
    }
    if (c < 2) {
        #pragma unroll
        for (int i = 0; i < 8; ++i) {
            int si = c*8 + i;
            d[240 + si] = f2bf(sv[(size_t)row*16 + si] * scale);
        }
    } else if (c == 2) {
        #pragma unroll
        for (int i = 0; i < 8; ++i) d[304 + i] = 0;
    } else if (c == 3) {
        #pragma unroll
        for (int i = 0; i < 8; ++i) d[312 + i] = 0;
    } else if (c == 4) {
        #pragma unroll
        for (int i = 0; i < 8; ++i) ml[48 + i] = 0;
    } else if (c == 5) {
        #pragma unroll
        for (int i = 0; i < 8; ++i) ml[56 + i] = 0;
    } else if (c == 6) {
        #pragma unroll
        for (int i = 0; i < 8; ++i) ml[112 + i] = 0;
    } else {
        #pragma unroll
        for (int i = 0; i < 8; ++i) ml[120 + i] = 0;
    }
}

// ---- stage 1b: V -> transposed bf16 [8][272][4096] ----
__global__ void vtrans_kernel(const float* __restrict__ vmv,
                              const float* __restrict__ vs,
                              unsigned short* __restrict__ dst)
{
    __shared__ unsigned short tile[64][DV];
    int blk = blockIdx.x;
    int h = blk >> 6;
    int n0 = (blk & 63) << 6;
    int t = threadIdx.x;
    #pragma unroll
    for (int it = 0; it < 16; ++it) {
        int v = t + it*256;
        int r = v >> 6;
        int sg = v & 63;
        float4 x = *(const float4*)(vmv + ((size_t)(h*NN + n0 + r))*256 + sg*4);
        tile[r][sg*4+0] = f2bf(x.x);
        tile[r][sg*4+1] = f2bf(x.y);
        tile[r][sg*4+2] = f2bf(x.z);
        tile[r][sg*4+3] = f2bf(x.w);
    }
    #pragma unroll
    for (int it = 0; it < 4; ++it) {
        int v = t + it*256;
        int r = v >> 4;
        int si = v & 15;
        tile[r][256 + si] = f2bf(vs[((size_t)(h*NN + n0 + r))*16 + si]);
    }
    __syncthreads();
    #pragma unroll
    for (int it = 0; it < 17; ++it) {      // 272 rows * 16 segs = 4352 = 17*256
        int v = t + it*256;
        int dd = v >> 4;
        int sg = v & 15;
        ushort4 o;
        o.x = tile[sg*4+0][dd];
        o.y = tile[sg*4+1][dd];
        o.z = tile[sg*4+2][dd];
        o.w = tile[sg*4+3][dd];
        *(ushort4*)(dst + ((size_t)(h*DV + dd))*NN + n0 + sg*4) = o;
    }
}

// ---- stage 2: flash attention, BM=64/BN=32, 2 blocks/CU ----
__global__ __launch_bounds__(256, 2)
void attn_kernel(const unsigned short* __restrict__ Qf,
                 const unsigned short* __restrict__ Kf,
                 const unsigned short* __restrict__ Qml,
                 const unsigned short* __restrict__ Kml,
                 const unsigned short* __restrict__ Vt,
                 float* __restrict__ out)
{
    __shared__ __align__(16) unsigned short kt_s[BN][KT_LD];
    __shared__ __align__(16) unsigned short km_s[BN][KM_LD];
    __shared__ __align__(16) unsigned short kl_s[BN][KM_LD];
    __shared__ __align__(16) unsigned short vt_s[DV][VT_LD];
    __shared__ __align__(16) unsigned short pb_s[NWAVE][MW][P_LD];

    int blk = blockIdx.x;
    // XCD swizzle: grid=512 (8|512) -> bijective; XCD x gets head x.
    int sbk = ((blk & 7) << 6) | (blk >> 3);
    int h = sbk >> 6;
    int q0 = (sbk & 63) * BM;
    int tid = threadIdx.x;
    int w = tid >> 6;
    int lane = tid & 63;
    int l15 = lane & 15;
    int l4 = lane >> 4;

    // Q fragments in registers (wave owns 16 q-rows)
    const unsigned short* qb = Qf + ((size_t)h*NN + q0 + w*MW + l15) * DQK + l4*8;
    const unsigned short* qm = Qml + ((size_t)h*NN + q0 + w*MW + l15) * DML + l4*8;
    bf16x8 qhi[10], qmid[2], qlo[2];
    #pragma unroll
    for (int ks = 0; ks < 10; ++ks)
        qhi[ks] = *(const bf16x8*)(qb + ks*32);
    #pragma unroll
    for (int ks = 0; ks < 2; ++ks) {
        qmid[ks] = *(const bf16x8*)(qm + ks*32);
        qlo[ks]  = *(const bf16x8*)(qm + 64 + ks*32);
    }

    f32x4 zero = {0.f, 0.f, 0.f, 0.f};
    f32x4 oacc[17];
    #pragma unroll
    for (int ct = 0; ct < 17; ++ct)
        oacc[ct] = zero;
    float mrow[4], lrow[4];
    #pragma unroll
    for (int j = 0; j < 4; ++j) { mrow[j] = -__builtin_inff(); lrow[j] = 0.f; }

    const unsigned short* kh  = Kf  + (size_t)h*NN*DQK;
    const unsigned short* kmh = Kml + (size_t)h*NN*DML;
    const unsigned short* vh  = Vt  + (size_t)h*DV*NN;

    for (int kt0 = 0; kt0 < NN; kt0 += BN) {
        // stage K hi tile: 32 rows * 40 segs = 1280 = 5*256
        #pragma unroll
        for (int it = 0; it < 5; ++it) {
            int v = tid + it*256;
            int r = v / 40;
            int sg = v - r*40;
            bf16x8 x = *(const bf16x8*)(kh + ((size_t)(kt0 + r))*DQK + sg*8);
            *(bf16x8*)&kt_s[r][sg*8] = x;
        }
        // stage K mid/lo tile: 32 rows * 16 segs = 512 = 2*256
        #pragma unroll
        for (int it = 0; it < 2; ++it) {
            int v = tid + it*256;
            int r = v >> 4;
            int sg = v & 15;
            bf16x8 x = *(const bf16x8*)(kmh + ((size_t)(kt0 + r))*DML + sg*8);
            if (sg < 8) *(bf16x8*)&km_s[r][sg*8] = x;
            else        *(bf16x8*)&kl_s[r][(sg-8)*8] = x;
        }
        // stage Vt tile: 272 rows * 4 segs = 1088
        #pragma unroll
        for (int it = 0; it < 5; ++it) {
            int v = tid + it*256;
            if (v < DV*4) {
                int r = v >> 2;
                int sg = v & 3;
                bf16x8 x = *(const bf16x8*)(vh + (size_t)r*NN + kt0 + sg*8);
                *(bf16x8*)&vt_s[r][sg*8] = x;
            }
        }
        __syncthreads();

        f32x4 sacc[2];
        sacc[0] = zero; sacc[1] = zero;

        // ip + s dims (0..255): single bf16 pass
        #pragma unroll
        for (int ks = 0; ks < 8; ++ks) {
            bf16x8 b0 = *(const bf16x8*)&kt_s[l15][ks*32 + l4*8];
            bf16x8 b1 = *(const bf16x8*)&kt_s[16 + l15][ks*32 + l4*8];
            sacc[0] = __builtin_amdgcn_mfma_f32_16x16x32_bf16(qhi[ks], b0, sacc[0], 0, 0, 0);
            sacc[1] = __builtin_amdgcn_mfma_f32_16x16x32_bf16(qhi[ks], b1, sacc[1], 0, 0, 0);
        }
        // dist dims (hi 256..319, 3-term split): hh, hm, mh, hl, lh, mm
        #pragma unroll
        for (int ks2 = 0; ks2 < 2; ++ks2) {
            #pragma unroll
            for (int ct = 0; ct < 2; ++ct) {
                bf16x8 bhi = *(const bf16x8*)&kt_s[ct*16 + l15][256 + ks2*32 + l4*8];
                bf16x8 bm  = *(const bf16x8*)&km_s[ct*16 + l15][ks2*32 + l4*8];
                bf16x8 bl  = *(const bf16x8*)&kl_s[ct*16 + l15][ks2*32 + l4*8];
                f32x4 a = sacc[ct];
                a = __builtin_amdgcn_mfma_f32_16x16x32_bf16(qhi[8+ks2], bhi, a, 0, 0, 0);
                a = __builtin_amdgcn_mfma_f32_16x16x32_bf16(qhi[8+ks2], bm,  a, 0, 0, 0);
                a = __builtin_amdgcn_mfma_f32_16x16x32_bf16(qmid[ks2],  bhi, a, 0, 0, 0);
                a = __builtin_amdgcn_mfma_f32_16x16x32_bf16(qhi[8+ks2], bl,  a, 0, 0, 0);
                a = __builtin_amdgcn_mfma_f32_16x16x32_bf16(qlo[ks2],   bhi, a, 0, 0, 0);
                a = __builtin_amdgcn_mfma_f32_16x16x32_bf16(qmid[ks2],  bm,  a, 0, 0, 0);
                sacc[ct] = a;
            }
        }

        // online softmax; S row = l4*4 + j (within wave's 16), col = ct*16 + l15
        #pragma unroll
        for (int j = 0; j < 4; ++j) {
            float tm = fmaxf(sacc[0][j], sacc[1][j]);
            tm = fmaxf(tm, __shfl_xor(tm, 1, 64));
            tm = fmaxf(tm, __shfl_xor(tm, 2, 64));
            tm = fmaxf(tm, __shfl_xor(tm, 4, 64));
            tm = fmaxf(tm, __shfl_xor(tm, 8, 64));
            float mold = mrow[j];
            float mnew = fmaxf(mold, tm);
            mrow[j] = mnew;
            float p0 = __expf(sacc[0][j] - mnew);
            float p1 = __expf(sacc[1][j] - mnew);
            float rs = p0 + p1;
            rs += __shfl_xor(rs, 1, 64);
            rs += __shfl_xor(rs, 2, 64);
            rs += __shfl_xor(rs, 4, 64);
            rs += __shfl_xor(rs, 8, 64);
            if (__all(mnew == mold)) {
                lrow[j] += rs;
            } else {
                float alpha = __expf(mold - mnew);   // 0 on first tile
                lrow[j] = lrow[j] * alpha + rs;
                #pragma unroll
                for (int ct = 0; ct < 17; ++ct)
                    oacc[ct][j] *= alpha;
            }
            int prow = l4*4 + j;
            pb_s[w][prow][ 0 + l15] = f2bf(p0);
            pb_s[w][prow][16 + l15] = f2bf(p1);
        }

        // PV: O += P(16x32) @ V(32x272)
        {
            bf16x8 pa = *(const bf16x8*)&pb_s[w][l15][l4*8];
            #pragma unroll
            for (int ct = 0; ct < 17; ++ct) {
                bf16x8 bv = *(const bf16x8*)&vt_s[ct*16 + l15][l4*8];
                oacc[ct] = __builtin_amdgcn_mfma_f32_16x16x32_bf16(pa, bv, oacc[ct], 0, 0, 0);
            }
        }
        __syncthreads();
    }

    // epilogue
    const size_t mv_total = (size_t)HH * NN * 256;
    #pragma unroll
    for (int j = 0; j < 4; ++j) {
        int q = q0 + w*MW + l4*4 + j;
        float inv = 1.0f / lrow[j];
        float* po = out + ((size_t)h*NN + q) * 256 + l15;
        #pragma unroll
        for (int ct = 0; ct < 16; ++ct)
            po[ct*16] = oacc[ct][j] * inv;
        out[mv_total + ((size_t)h*NN + q)*16 + l15] = oacc[16][j] * inv;
    }
}

extern "C" void kernel_launch(void* const* d_in, const int* in_sizes, int n_in,
                              void* d_out, int out_size, void* d_ws, size_t ws_size,
                              hipStream_t stream)
{
    const float* q_mv = (const float*)d_in[0];
    const float* k_mv = (const float*)d_in[1];
    const float* v_mv = (const float*)d_in[2];
    const float* q_s  = (const float*)d_in[3];
    const float* k_s  = (const float*)d_in[4];
    const float* v_s  = (const float*)d_in[5];
    const float* basis_q = (const float*)d_in[6];
    const float* basis_k = (const float*)d_in[7];
    float* out = (float*)d_out;

    unsigned short* qf  = (unsigned short*)d_ws;                  // [8][4096][320]
    unsigned short* kf  = qf  + (size_t)HH*NN*DQK;                // [8][4096][320]
    unsigned short* qml = kf  + (size_t)HH*NN*DQK;                // [8][4096][128]
    unsigned short* kml = qml + (size_t)HH*NN*DML;                // [8][4096][128]
    unsigned short* vt  = kml + (size_t)HH*NN*DML;                // [8][272][4096]
    // total ws use: 76,546,048 bytes

    const float qscale = 0.05735393346764042f;  // 1/sqrt(304); k-rescale is exactly 1

    feat_kernel<<<dim3(1024), dim3(256), 0, stream>>>(q_mv, q_s, basis_q, qscale, qf, qml);
    feat_kernel<<<dim3(1024), dim3(256), 0, stream>>>(k_mv, k_s, basis_k, 1.0f, kf, kml);
    vtrans_kernel<<<dim3(512), dim3(256), 0, stream>>>(v_mv, v_s, vt);
    attn_kernel<<<dim3(512), dim3(256), 0, stream>>>(qf, kf, qml, kml, vt, out);
}